// Round 4
// baseline (150.461 us; speedup 1.0000x reference)
//
#include <hip/hip_runtime.h>
#include <cstdint>

// ---------------- problem constants ----------------
#define H_IN   128
#define W_IN   128
#define C_IN   256
#define O_OUT  256
#define OH     126
#define OW     126

// ---------------- tiling ----------------
#define TY     8                // output tile height
#define TX     8                // output tile width  (64 px = 1 px/lane)
#define IR     (TY + 2)         // 10 input rows staged
#define ICOLS  (TX + 2)         // 10 input cols staged
#define NPIX   (IR * ICOLS)     // 100 staged pixels
#define COLB   516              // bytes per staged pixel (256 bf16 + 2 pad hw)
                                //   word-stride 129 = 1 mod 32
#define ROWB   5264             // bytes per staged row: 10*516=5160 +104 pad
                                //   word-stride 1316 = 4 mod 32
                                //   gather bank = (4r + c) mod 32: r,c in [0,8)
                                //   covers every bank EXACTLY 2x -> free (m136)
#define IN_BYTES (9 * ROWB + 9 * COLB + COLB)   // 52536 B input region
#define NWAVES 8
#define OPW    32               // output channels per wave
#define SST    34               // flush-stage word stride (even -> 8B-aligned float2)
#define STG_W  (64 * SST)       // 2176 words per wave
#define FLUSH_BYTES (4 * STG_W * 4)      // 34816 B: 4 waves per flush pass
#define LDS_BYTES IN_BYTES               // 52536 -> 3 blocks/CU (157608 <= 163840)

// ---------------- prep: build padded channel-interleaved entry table ----------
// Channels grouped 8-wide: subgroup sg = o>>3 (32 subgroups, 4 per wave).
// Subgroup sg padded to S[sg] = max per-channel count; table row (slot) holds
// 8 entries (one per channel j=o&7), dummies are (meta=0, val=0).
// meta pre-scaled to BYTES so the hot loop is addr-add + fmac only.
__global__ void prep_kernel(const int* __restrict__ wi, const float* __restrict__ wv,
                            int nnz, int* __restrict__ sgS, int* __restrict__ sgBase,
                            int2* __restrict__ tab) {
    __shared__ int cnt[256];
    __shared__ int smax[32];
    __shared__ int sbase[33];
    __shared__ int is32;
    const int tid = threadIdx.x;
    cnt[tid] = 0;
    if (tid == 0) is32 = 0;
    __syncthreads();
    // dtype detect: int32 layout has nonzero odd words (ih/ic); int64 highs are 0
    int f = 0;
    for (int idx = tid * 2 + 1; idx < nnz * 4; idx += 512) f |= wi[idx];
    if (f) atomicOr(&is32, 1);
    __syncthreads();
    const int stride = is32 ? 4 : 8;
    const int step   = is32 ? 1 : 2;
    for (int e = tid; e < nnz; e += 256)
        atomicAdd(&cnt[wi[e * stride]], 1);
    __syncthreads();
    if (tid < 32) {
        int m = 0;
        for (int k = 0; k < 8; ++k) m = max(m, cnt[tid * 8 + k]);
        smax[tid] = m;
    }
    __syncthreads();
    if (tid == 0) {
        int s = 0;
        for (int i = 0; i < 32; ++i) { sbase[i] = s; s += 8 * smax[i]; }
        sbase[32] = s;
    }
    __syncthreads();
    const int T = sbase[32];
    for (int i = tid; i < T; i += 256) tab[i] = make_int2(0, 0);  // dummy: lds[A2+0] * 0.0f
    cnt[tid] = 0;            // reuse as per-channel slot cursor
    __syncthreads();
    for (int e = tid; e < nnz; e += 256) {
        int o  = wi[e * stride];
        int h  = wi[e * stride + 1 * step];
        int w_ = wi[e * stride + 2 * step];
        int c  = wi[e * stride + 3 * step];
        // faithful scrambled mapping: flat k in (kh,kw,C), reinterpreted as (C,kh,kw)
        int k   = h * 768 + w_ * 256 + c;
        int cp  = k / 9;
        int rem = k - cp * 9;
        int i_  = rem / 3;
        int j_  = rem - i_ * 3;
        int meta2 = i_ * ROWB + j_ * COLB + cp * 2;   // LDS BYTE delta for tap/channel
        int slot = atomicAdd(&cnt[o], 1);             // duplicates get distinct slots (summed)
        tab[sbase[o >> 3] + slot * 8 + (o & 7)] = make_int2(meta2, __float_as_int(wv[e]));
    }
    if (tid < 32) sgS[tid] = smax[tid];
    if (tid < 33) sgBase[tid] = sbase[tid];
}

// round-to-nearest-even fp32 -> bf16 bits
__device__ inline unsigned short rtne_bf16(float f) {
    unsigned u = __float_as_uint(f);
    u += 0x7FFFu + ((u >> 16) & 1u);
    return (unsigned short)(u >> 16);
}

__device__ __forceinline__ float bfld(const char* b, int off) {
    return __uint_as_float(((unsigned)*(const unsigned short*)(b + off)) << 16);
}

// ---------------- main conv kernel ----------------
// 3 blocks/CU (LDS 52536*3 <= 160K), 6 waves/SIMD -> VGPR budget 85
__global__ __launch_bounds__(512, 6)
void conv_kernel(const float* __restrict__ in, float* __restrict__ out,
                 const int* __restrict__ sgS, const int* __restrict__ sgBase,
                 const int2* __restrict__ tab) {
    extern __shared__ char smem[];
    float* ldsF = (float*)smem;

    const int tid  = threadIdx.x;
    const int w    = __builtin_amdgcn_readfirstlane(tid >> 6);  // wave-uniform in SGPR
    const int lane = tid & 63;
    const int tx = blockIdx.x, ty = blockIdx.y, b = blockIdx.z;
    const int iy0 = ty * TY, ix0 = tx * TX;
    const float* inb = in + (size_t)b * (H_IN * W_IN * C_IN);

    // ---- stage input tile: 100 px x 256 ch fp32 -> bf16 in LDS ----
    // wave handles whole pixel: 64 lanes x float4 (1 KB coalesced read).
    // 4-deep load batching so HBM latency amortizes across independent loads.
    for (int base = 0; base < 16; base += 4) {
        float4 v[4];
#pragma unroll
        for (int q = 0; q < 4; ++q) {
            int p = w + (base + q) * NWAVES;
            if (p < NPIX) {
                int r = p / ICOLS, c = p - r * ICOLS;
                int gy = iy0 + r, gx = ix0 + c;
                if (gy < H_IN && gx < W_IN)   // wave-uniform
                    v[q] = *(const float4*)(inb + ((gy * W_IN + gx) << 8) + (lane << 2));
            }
        }
#pragma unroll
        for (int q = 0; q < 4; ++q) {
            int p = w + (base + q) * NWAVES;
            if (p < NPIX) {
                int r = p / ICOLS, c = p - r * ICOLS;
                int gy = iy0 + r, gx = ix0 + c;
                if (gy < H_IN && gx < W_IN) {
                    ushort2 lo, hi;
                    lo.x = rtne_bf16(v[q].x); lo.y = rtne_bf16(v[q].y);
                    hi.x = rtne_bf16(v[q].z); hi.y = rtne_bf16(v[q].w);
                    unsigned short* d = (unsigned short*)(smem + r * ROWB + c * COLB) + (lane << 2);
                    *(ushort2*)(d)     = lo;           // 4B-aligned b32 writes, stride-2 banks
                    *(ushort2*)(d + 2) = hi;
                }
            }
        }
    }
    __syncthreads();

    // ---- gather: lane = output pixel (8x8); wave owns 32 ch in 4 subgroups of 8 ----
    // bank(lane) = (4r + c) mod 32 -> exactly 2 lanes per bank -> conflict-free
    const int A2  = (lane >> 3) * ROWB + (lane & 7) * COLB;   // byte base of lane's pixel
    const int sgb = w * 4;
    const char* basep = (const char*)smem;
    float acc[OPW];
#pragma unroll
    for (int i = 0; i < OPW; ++i) acc[i] = 0.f;

#pragma unroll
    for (int g = 0; g < 4; ++g) {
        const int S = sgS[sgb + g];
        const int2* Tg = tab + sgBase[sgb + g];
        for (int slot = 0; slot < S; ++slot) {
            const int4* R = (const int4*)(Tg + (slot << 3));   // 64 B, wave-uniform, cache-hot
            const int4 p0 = R[0];
            const int4 p1 = R[1];
            const int4 p2 = R[2];
            const int4 p3 = R[3];
            acc[g * 8 + 0] += __int_as_float(p0.y) * bfld(basep, A2 + p0.x);
            acc[g * 8 + 1] += __int_as_float(p0.w) * bfld(basep, A2 + p0.z);
            acc[g * 8 + 2] += __int_as_float(p1.y) * bfld(basep, A2 + p1.x);
            acc[g * 8 + 3] += __int_as_float(p1.w) * bfld(basep, A2 + p1.z);
            acc[g * 8 + 4] += __int_as_float(p2.y) * bfld(basep, A2 + p2.x);
            acc[g * 8 + 5] += __int_as_float(p2.w) * bfld(basep, A2 + p2.z);
            acc[g * 8 + 6] += __int_as_float(p3.y) * bfld(basep, A2 + p3.x);
            acc[g * 8 + 7] += __int_as_float(p3.w) * bfld(basep, A2 + p3.z);
        }
    }

    // ---- flush: input region dead; two passes of 4 waves reuse it as transpose stage ----
    __syncthreads();                                   // (B1) input region dead
    const int ob = w * OPW;
    const int wq = w & 3;
    // pass 0: waves 0-3
    if (w < 4) {
        float* st = ldsF + wq * STG_W + lane * SST;
#pragma unroll
        for (int k = 0; k < OPW; k += 2)
            *(float2*)(st + k) = make_float2(acc[k], acc[k + 1]);
    }
    __syncthreads();                                   // (B2)
    if (w < 4) {
        const int a_  = lane >> 3;     // pixel sub-index 0..7
        const int chq = lane & 7;      // channel quad 0..7
        const float* rb = ldsF + wq * STG_W;
#pragma unroll
        for (int s8 = 0; s8 < 8; ++s8) {
            int p = s8 * 8 + a_;
            float2 u0 = *(const float2*)(rb + p * SST + chq * 4);
            float2 u1 = *(const float2*)(rb + p * SST + chq * 4 + 2);
            int poy = iy0 + (p >> 3), pox = ix0 + (p & 7);
            if (poy < OH && pox < OW) {
                float4 o4 = make_float4(u0.x, u0.y, u1.x, u1.y);
                *(float4*)(out + (((size_t)b * OH + poy) * OW + pox) * O_OUT + ob + chq * 4) = o4;
            }
        }
    }
    __syncthreads();                                   // (B3) pass-0 reads done
    // pass 1: waves 4-7
    if (w >= 4) {
        float* st = ldsF + wq * STG_W + lane * SST;
#pragma unroll
        for (int k = 0; k < OPW; k += 2)
            *(float2*)(st + k) = make_float2(acc[k], acc[k + 1]);
    }
    __syncthreads();                                   // (B4)
    if (w >= 4) {
        const int a_  = lane >> 3;
        const int chq = lane & 7;
        const float* rb = ldsF + wq * STG_W;
#pragma unroll
        for (int s8 = 0; s8 < 8; ++s8) {
            int p = s8 * 8 + a_;
            float2 u0 = *(const float2*)(rb + p * SST + chq * 4);
            float2 u1 = *(const float2*)(rb + p * SST + chq * 4 + 2);
            int poy = iy0 + (p >> 3), pox = ix0 + (p & 7);
            if (poy < OH && pox < OW) {
                float4 o4 = make_float4(u0.x, u0.y, u1.x, u1.y);
                *(float4*)(out + (((size_t)b * OH + poy) * OW + pox) * O_OUT + ob + chq * 4) = o4;
            }
        }
    }
}

// ---------------- host ----------------
extern "C" void kernel_launch(void* const* d_in, const int* in_sizes, int n_in,
                              void* d_out, int out_size, void* d_ws, size_t ws_size,
                              hipStream_t stream) {
    const float* input = (const float*)d_in[0];
    const int*   widx  = (const int*)d_in[1];    // int32 or int64 (runtime-detected)
    const float* wval  = (const float*)d_in[2];
    float* outp = (float*)d_out;
    const int nnz = in_sizes[2];
    const int B = in_sizes[0] / (H_IN * W_IN * C_IN);

    int*  sgS    = (int*)d_ws;                       // 32 ints
    int*  sgBase = sgS + 32;                         // 33 ints
    int2* tab    = (int2*)((char*)d_ws + 512);       // 16B-aligned; worst case 8*nnz entries

    prep_kernel<<<1, 256, 0, stream>>>(widx, wval, nnz, sgS, sgBase, tab);

    static_assert(LDS_BYTES >= FLUSH_BYTES, "flush pass must fit in input region");
    static_assert(3 * LDS_BYTES <= 160 * 1024, "need 3 blocks/CU");
    hipFuncSetAttribute((const void*)conv_kernel,
                        hipFuncAttributeMaxDynamicSharedMemorySize, LDS_BYTES);
    dim3 grid((OW + TX - 1) / TX, (OH + TY - 1) / TY, B);
    conv_kernel<<<grid, 512, LDS_BYTES, stream>>>(input, outp, sgS, sgBase, tab);
}

// Round 5
// 142.594 us; speedup vs baseline: 1.0552x; 1.0552x over previous
//
#include <hip/hip_runtime.h>
#include <cstdint>

// ---------------- problem constants ----------------
#define H_IN   128
#define W_IN   128
#define C_IN   256
#define O_OUT  256
#define OH     126
#define OW     126

// ---------------- tiling ----------------
#define TY     8                // output tile height
#define TX     8                // output tile width  (64 px = 1 px/lane)
#define IR     (TY + 2)         // 10 input rows staged
#define ICOLS  (TX + 2)         // 10 input cols staged
#define NPIX   (IR * ICOLS)     // 100 staged pixels
#define COLB   516              // bytes per staged pixel (256 bf16 + 2 pad hw)
#define ROWB   5264             // bytes per staged row (pad: word-stride 4 mod 32)
#define IN_BYTES (9 * ROWB + 9 * COLB + COLB)   // 52536 B input region
#define NWAVES 16               // 1024-thread blocks
#define OPW    16               // output channels per wave
#define SST    18               // flush-stage word stride per pixel (16 ch + 2 pad)
#define STG_W  (64 * SST)       // 1152 words per wave region
#define FLUSH_BYTES (8 * STG_W * 4)      // 36864 B: 8 waves per flush pass
#define LDS_BYTES IN_BYTES               // 52536 -> 2 blocks/CU = 32 waves = 100% cap

// ---------------- prep: build padded channel-interleaved entry table ----------
// Channels grouped 8-wide: subgroup sg = o>>3 (32 subgroups, 2 per wave).
// Subgroup sg padded to S[sg] = max per-channel count; table row (slot) holds
// 8 entries (one per channel j=o&7), dummies are (meta=0, val=0).
// meta pre-scaled to BYTES so the hot loop is addr-add + fmac only.
__global__ void prep_kernel(const int* __restrict__ wi, const float* __restrict__ wv,
                            int nnz, int* __restrict__ sgS, int* __restrict__ sgBase,
                            int2* __restrict__ tab) {
    __shared__ int cnt[256];
    __shared__ int smax[32];
    __shared__ int sbase[33];
    __shared__ int is32;
    const int tid = threadIdx.x;
    cnt[tid] = 0;
    if (tid == 0) is32 = 0;
    __syncthreads();
    // dtype detect: int32 layout has nonzero odd words (ih/ic); int64 highs are 0
    int f = 0;
    for (int idx = tid * 2 + 1; idx < nnz * 4; idx += 512) f |= wi[idx];
    if (f) atomicOr(&is32, 1);
    __syncthreads();
    const int stride = is32 ? 4 : 8;
    const int step   = is32 ? 1 : 2;
    for (int e = tid; e < nnz; e += 256)
        atomicAdd(&cnt[wi[e * stride]], 1);
    __syncthreads();
    if (tid < 32) {
        int m = 0;
        for (int k = 0; k < 8; ++k) m = max(m, cnt[tid * 8 + k]);
        smax[tid] = m;
    }
    __syncthreads();
    if (tid == 0) {
        int s = 0;
        for (int i = 0; i < 32; ++i) { sbase[i] = s; s += 8 * smax[i]; }
        sbase[32] = s;
    }
    __syncthreads();
    const int T = sbase[32];
    for (int i = tid; i < T; i += 256) tab[i] = make_int2(0, 0);  // dummy: lds[A2+0] * 0.0f
    cnt[tid] = 0;            // reuse as per-channel slot cursor
    __syncthreads();
    for (int e = tid; e < nnz; e += 256) {
        int o  = wi[e * stride];
        int h  = wi[e * stride + 1 * step];
        int w_ = wi[e * stride + 2 * step];
        int c  = wi[e * stride + 3 * step];
        // faithful scrambled mapping: flat k in (kh,kw,C), reinterpreted as (C,kh,kw)
        int k   = h * 768 + w_ * 256 + c;
        int cp  = k / 9;
        int rem = k - cp * 9;
        int i_  = rem / 3;
        int j_  = rem - i_ * 3;
        int meta2 = i_ * ROWB + j_ * COLB + cp * 2;   // LDS BYTE delta for tap/channel
        int slot = atomicAdd(&cnt[o], 1);             // duplicates get distinct slots (summed)
        tab[sbase[o >> 3] + slot * 8 + (o & 7)] = make_int2(meta2, __float_as_int(wv[e]));
    }
    if (tid < 32) sgS[tid] = smax[tid];
    if (tid < 33) sgBase[tid] = sbase[tid];
}

// round-to-nearest-even fp32 -> bf16 bits
__device__ inline unsigned short rtne_bf16(float f) {
    unsigned u = __float_as_uint(f);
    u += 0x7FFFu + ((u >> 16) & 1u);
    return (unsigned short)(u >> 16);
}

__device__ __forceinline__ float bfld(const char* b, int off) {
    return __uint_as_float(((unsigned)*(const unsigned short*)(b + off)) << 16);
}

// ---------------- main conv kernel ----------------
// 1024 threads = 16 waves; 2 blocks/CU (LDS 52536*2) -> 32 waves/CU = 100% cap.
// 8 waves/SIMD requires VGPR <= 64 (acc[16] keeps us well under).
__global__ __launch_bounds__(1024, 8)
void conv_kernel(const float* __restrict__ in, float* __restrict__ out,
                 const int* __restrict__ sgS, const int* __restrict__ sgBase,
                 const int2* __restrict__ tab) {
    extern __shared__ char smem[];
    float* ldsF = (float*)smem;

    const int tid  = threadIdx.x;
    const int w    = __builtin_amdgcn_readfirstlane(tid >> 6);  // wave id 0..15 in SGPR
    const int lane = tid & 63;
    const int tx = blockIdx.x, ty = blockIdx.y, b = blockIdx.z;
    const int iy0 = ty * TY, ix0 = tx * TX;
    const float* inb = in + (size_t)b * (H_IN * W_IN * C_IN);

    // ---- stage input tile: 100 px x 256 ch fp32 -> bf16 in LDS ----
    // wave handles whole pixel: 64 lanes x float4 (1 KB coalesced read).
    // 4-deep load batching so HBM latency amortizes across independent loads.
    for (int base = 0; base < 8; base += 4) {
        float4 v[4];
#pragma unroll
        for (int q = 0; q < 4; ++q) {
            int p = w + (base + q) * NWAVES;
            if (p < NPIX) {
                int r = p / ICOLS, c = p - r * ICOLS;
                int gy = iy0 + r, gx = ix0 + c;
                if (gy < H_IN && gx < W_IN)   // wave-uniform
                    v[q] = *(const float4*)(inb + ((gy * W_IN + gx) << 8) + (lane << 2));
            }
        }
#pragma unroll
        for (int q = 0; q < 4; ++q) {
            int p = w + (base + q) * NWAVES;
            if (p < NPIX) {
                int r = p / ICOLS, c = p - r * ICOLS;
                int gy = iy0 + r, gx = ix0 + c;
                if (gy < H_IN && gx < W_IN) {
                    ushort2 lo, hi;
                    lo.x = rtne_bf16(v[q].x); lo.y = rtne_bf16(v[q].y);
                    hi.x = rtne_bf16(v[q].z); hi.y = rtne_bf16(v[q].w);
                    unsigned short* d = (unsigned short*)(smem + r * ROWB + c * COLB) + (lane << 2);
                    *(ushort2*)(d)     = lo;           // 4B-aligned b32 writes
                    *(ushort2*)(d + 2) = hi;
                }
            }
        }
    }
    __syncthreads();

    // ---- gather: lane = output pixel (8x8); wave owns 16 ch in 2 subgroups of 8 ----
    const int A2  = (lane >> 3) * ROWB + (lane & 7) * COLB;   // byte base of lane's pixel
    const int sgb = w * 2;
    const char* basep = (const char*)smem;
    float acc[OPW];
#pragma unroll
    for (int i = 0; i < OPW; ++i) acc[i] = 0.f;

#pragma unroll
    for (int g = 0; g < 2; ++g) {
        const int S = sgS[sgb + g];
        const int2* Tg = tab + sgBase[sgb + g];
        for (int slot = 0; slot < S; ++slot) {
            const int4* R = (const int4*)(Tg + (slot << 3));   // 64 B, wave-uniform, cache-hot
            const int4 p0 = R[0];
            const int4 p1 = R[1];
            const int4 p2 = R[2];
            const int4 p3 = R[3];
            acc[g * 8 + 0] += __int_as_float(p0.y) * bfld(basep, A2 + p0.x);
            acc[g * 8 + 1] += __int_as_float(p0.w) * bfld(basep, A2 + p0.z);
            acc[g * 8 + 2] += __int_as_float(p1.y) * bfld(basep, A2 + p1.x);
            acc[g * 8 + 3] += __int_as_float(p1.w) * bfld(basep, A2 + p1.z);
            acc[g * 8 + 4] += __int_as_float(p2.y) * bfld(basep, A2 + p2.x);
            acc[g * 8 + 5] += __int_as_float(p2.w) * bfld(basep, A2 + p2.z);
            acc[g * 8 + 6] += __int_as_float(p3.y) * bfld(basep, A2 + p3.x);
            acc[g * 8 + 7] += __int_as_float(p3.w) * bfld(basep, A2 + p3.z);
        }
    }

    // ---- flush: input region dead; two passes of 8 waves reuse it as transpose stage ----
    __syncthreads();                                   // (B1) input region dead
    const int ob = w * OPW;
    const int wq = w & 7;
    // pass 0: waves 0-7
    if (w < 8) {
        float* st = ldsF + wq * STG_W + lane * SST;
#pragma unroll
        for (int k = 0; k < OPW; k += 2)
            *(float2*)(st + k) = make_float2(acc[k], acc[k + 1]);
    }
    __syncthreads();                                   // (B2)
    if (w < 8) {
        const int a_  = lane >> 2;     // pixel sub-index 0..15
        const int chq = lane & 3;      // channel quad 0..3
        const float* rb = ldsF + wq * STG_W;
#pragma unroll
        for (int s16 = 0; s16 < 4; ++s16) {
            int p = s16 * 16 + a_;
            float2 u0 = *(const float2*)(rb + p * SST + chq * 4);
            float2 u1 = *(const float2*)(rb + p * SST + chq * 4 + 2);
            int poy = iy0 + (p >> 3), pox = ix0 + (p & 7);
            if (poy < OH && pox < OW) {
                float4 o4 = make_float4(u0.x, u0.y, u1.x, u1.y);
                // 4 lanes per pixel -> 64 B contiguous segment
                *(float4*)(out + (((size_t)b * OH + poy) * OW + pox) * O_OUT + ob + chq * 4) = o4;
            }
        }
    }
    __syncthreads();                                   // (B3) pass-0 reads done
    // pass 1: waves 8-15
    if (w >= 8) {
        float* st = ldsF + wq * STG_W + lane * SST;
#pragma unroll
        for (int k = 0; k < OPW; k += 2)
            *(float2*)(st + k) = make_float2(acc[k], acc[k + 1]);
    }
    __syncthreads();                                   // (B4)
    if (w >= 8) {
        const int a_  = lane >> 2;
        const int chq = lane & 3;
        const float* rb = ldsF + wq * STG_W;
#pragma unroll
        for (int s16 = 0; s16 < 4; ++s16) {
            int p = s16 * 16 + a_;
            float2 u0 = *(const float2*)(rb + p * SST + chq * 4);
            float2 u1 = *(const float2*)(rb + p * SST + chq * 4 + 2);
            int poy = iy0 + (p >> 3), pox = ix0 + (p & 7);
            if (poy < OH && pox < OW) {
                float4 o4 = make_float4(u0.x, u0.y, u1.x, u1.y);
                *(float4*)(out + (((size_t)b * OH + poy) * OW + pox) * O_OUT + ob + chq * 4) = o4;
            }
        }
    }
}

// ---------------- host ----------------
extern "C" void kernel_launch(void* const* d_in, const int* in_sizes, int n_in,
                              void* d_out, int out_size, void* d_ws, size_t ws_size,
                              hipStream_t stream) {
    const float* input = (const float*)d_in[0];
    const int*   widx  = (const int*)d_in[1];    // int32 or int64 (runtime-detected)
    const float* wval  = (const float*)d_in[2];
    float* outp = (float*)d_out;
    const int nnz = in_sizes[2];
    const int B = in_sizes[0] / (H_IN * W_IN * C_IN);

    int*  sgS    = (int*)d_ws;                       // 32 ints
    int*  sgBase = sgS + 32;                         // 33 ints
    int2* tab    = (int2*)((char*)d_ws + 512);       // 16B-aligned; worst case 8*nnz entries

    prep_kernel<<<1, 256, 0, stream>>>(widx, wval, nnz, sgS, sgBase, tab);

    static_assert(LDS_BYTES >= FLUSH_BYTES, "flush pass must fit in input region");
    static_assert(2 * LDS_BYTES <= 160 * 1024, "need 2 blocks/CU");
    hipFuncSetAttribute((const void*)conv_kernel,
                        hipFuncAttributeMaxDynamicSharedMemorySize, LDS_BYTES);
    dim3 grid((OW + TX - 1) / TX, (OH + TY - 1) / TY, B);
    conv_kernel<<<grid, 1024, LDS_BYTES, stream>>>(input, outp, sgS, sgBase, tab);
}

// Round 6
// 140.909 us; speedup vs baseline: 1.0678x; 1.0120x over previous
//
#include <hip/hip_runtime.h>
#include <cstdint>

// ---------------- problem constants ----------------
#define H_IN   128
#define W_IN   128
#define C_IN   256
#define O_OUT  256
#define OH     126
#define OW     126

// ---------------- tiling ----------------
#define TY     8                // output tile height
#define TX     8                // output tile width  (64 px = 1 px/lane)
#define IR     (TY + 2)         // 10 input rows staged
#define ICOLS  (TX + 2)         // 10 input cols staged
#define NPIX   (IR * ICOLS)     // 100 staged pixels
#define COLB   516              // bytes per staged pixel (256 bf16 + 2 pad hw)
#define ROWB   5264             // bytes per staged row (pad: word-stride 4 mod 32)
#define IN_BYTES (9 * ROWB + 9 * COLB + COLB)   // 52536 B input region
#define NWAVES 16               // 1024-thread blocks
#define OPW    16               // output channels per wave
#define SST    18               // flush-stage word stride per pixel (16 ch + 2 pad)
#define STG_W  (64 * SST)       // 1152 words per wave region
#define FLUSH_BYTES (8 * STG_W * 4)      // 36864 B: 8 waves per flush pass
#define LDS_BYTES IN_BYTES               // 52536 -> 2 blocks/CU = 32 waves = 100% cap

// ---------------- prep: count-sorted grouping + padded entry table ----------
// Channels sorted by nnz count (desc); sorted position p: group g=p>>3, col=p&7.
// Group g padded to S[g]=max count within group (sorted neighbors -> minimal pad).
// Wave w processes groups {w, 31-w} (balanced totals). perm[] lets the conv
// kernel route accumulators back to true output channels during the flush.
__global__ void prep_kernel(const int* __restrict__ wi, const float* __restrict__ wv,
                            int nnz, int* __restrict__ sgS, int* __restrict__ sgBase,
                            int* __restrict__ perm, int2* __restrict__ tab) {
    __shared__ int cnt[256];
    __shared__ int ipos[256];
    __shared__ int prm[256];
    __shared__ int hist[64];
    __shared__ int hbase[65];
    __shared__ int hcur[64];
    __shared__ int smax[32];
    __shared__ int sbase[33];
    __shared__ int is32;
    const int tid = threadIdx.x;
    cnt[tid] = 0;
    if (tid < 64) { hist[tid] = 0; hcur[tid] = 0; }
    if (tid == 0) is32 = 0;
    __syncthreads();
    // dtype detect: int32 layout has nonzero odd words (ih/ic); int64 highs are 0
    int f = 0;
    for (int idx = tid * 2 + 1; idx < nnz * 4; idx += 512) f |= wi[idx];
    if (f) atomicOr(&is32, 1);
    __syncthreads();
    const int stride = is32 ? 4 : 8;
    const int step   = is32 ? 1 : 2;
    for (int e = tid; e < nnz; e += 256)
        atomicAdd(&cnt[wi[e * stride]], 1);
    __syncthreads();
    // counting sort of channels by count, descending (key = 63 - clamped count)
    { int key = 63 - min(cnt[tid], 63); atomicAdd(&hist[key], 1); }
    __syncthreads();
    if (tid == 0) {
        int s = 0;
        for (int i = 0; i < 64; ++i) { hbase[i] = s; s += hist[i]; }
        hbase[64] = s;
    }
    __syncthreads();
    { int key = 63 - min(cnt[tid], 63);
      int pos = hbase[key] + atomicAdd(&hcur[key], 1);
      ipos[tid] = pos; prm[pos] = tid; }
    __syncthreads();
    if (tid < 32) {
        int m = 0;
        for (int k = 0; k < 8; ++k) m = max(m, cnt[prm[tid * 8 + k]]);
        smax[tid] = m;
    }
    __syncthreads();
    if (tid == 0) {
        int s = 0;
        for (int i = 0; i < 32; ++i) { sbase[i] = s; s += 8 * smax[i]; }
        sbase[32] = s;
    }
    __syncthreads();
    const int T = sbase[32];
    for (int i = tid; i < T; i += 256) tab[i] = make_int2(0, 0);  // dummy: lds[A2+0] * 0.0f
    cnt[tid] = 0;            // reuse as per-channel slot cursor
    __syncthreads();
    for (int e = tid; e < nnz; e += 256) {
        int o  = wi[e * stride];
        int h  = wi[e * stride + 1 * step];
        int w_ = wi[e * stride + 2 * step];
        int c  = wi[e * stride + 3 * step];
        // faithful scrambled mapping: flat k in (kh,kw,C), reinterpreted as (C,kh,kw)
        int k   = h * 768 + w_ * 256 + c;
        int cp  = k / 9;
        int rem = k - cp * 9;
        int i_  = rem / 3;
        int j_  = rem - i_ * 3;
        int meta2 = i_ * ROWB + j_ * COLB + cp * 2;   // LDS BYTE delta for tap/channel
        int slot = atomicAdd(&cnt[o], 1);             // duplicates get distinct slots (summed)
        int p    = ipos[o];
        tab[sbase[p >> 3] + slot * 8 + (p & 7)] = make_int2(meta2, __float_as_int(wv[e]));
    }
    if (tid < 32) sgS[tid] = smax[tid];
    if (tid < 33) sgBase[tid] = sbase[tid];
    perm[tid] = prm[tid];
}

// round-to-nearest-even fp32 -> bf16 bits
__device__ inline unsigned short rtne_bf16(float f) {
    unsigned u = __float_as_uint(f);
    u += 0x7FFFu + ((u >> 16) & 1u);
    return (unsigned short)(u >> 16);
}

__device__ __forceinline__ float bfld(const char* b, int off) {
    return __uint_as_float(((unsigned)*(const unsigned short*)(b + off)) << 16);
}

// ---------------- main conv kernel ----------------
// 1024 threads = 16 waves; 2 blocks/CU (LDS 52536*2) -> 32 waves/CU = 100% cap.
__global__ __launch_bounds__(1024, 8)
void conv_kernel(const float* __restrict__ in, float* __restrict__ out,
                 const int* __restrict__ sgS, const int* __restrict__ sgBase,
                 const int* __restrict__ perm, const int2* __restrict__ tab) {
    extern __shared__ char smem[];
    float* ldsF = (float*)smem;

    const int tid  = threadIdx.x;
    const int w    = __builtin_amdgcn_readfirstlane(tid >> 6);  // wave id 0..15 in SGPR
    const int lane = tid & 63;
    const int tx = blockIdx.x, ty = blockIdx.y, b = blockIdx.z;
    const int iy0 = ty * TY, ix0 = tx * TX;
    const float* inb = in + (size_t)b * (H_IN * W_IN * C_IN);

    // ---- stage input tile: 100 px x 256 ch fp32 -> bf16 in LDS ----
    for (int base = 0; base < 8; base += 4) {
        float4 v[4];
#pragma unroll
        for (int q = 0; q < 4; ++q) {
            int p = w + (base + q) * NWAVES;
            if (p < NPIX) {
                int r = p / ICOLS, c = p - r * ICOLS;
                int gy = iy0 + r, gx = ix0 + c;
                if (gy < H_IN && gx < W_IN)   // wave-uniform
                    v[q] = *(const float4*)(inb + ((gy * W_IN + gx) << 8) + (lane << 2));
            }
        }
#pragma unroll
        for (int q = 0; q < 4; ++q) {
            int p = w + (base + q) * NWAVES;
            if (p < NPIX) {
                int r = p / ICOLS, c = p - r * ICOLS;
                int gy = iy0 + r, gx = ix0 + c;
                if (gy < H_IN && gx < W_IN) {
                    ushort2 lo, hi;
                    lo.x = rtne_bf16(v[q].x); lo.y = rtne_bf16(v[q].y);
                    hi.x = rtne_bf16(v[q].z); hi.y = rtne_bf16(v[q].w);
                    unsigned short* d = (unsigned short*)(smem + r * ROWB + c * COLB) + (lane << 2);
                    *(ushort2*)(d)     = lo;
                    *(ushort2*)(d + 2) = hi;
                }
            }
        }
    }
    __syncthreads();

    // ---- gather: lane = output pixel (8x8); wave owns sorted groups {w, 31-w} ----
    const int A2  = (lane >> 3) * ROWB + (lane & 7) * COLB;   // byte base of lane's pixel
    const int g0 = w, g1 = 31 - w;
    const char* basep = (const char*)smem;
    float acc[OPW];
#pragma unroll
    for (int i = 0; i < OPW; ++i) acc[i] = 0.f;

#pragma unroll
    for (int g = 0; g < 2; ++g) {
        const int gi = g ? g1 : g0;
        const int S = sgS[gi];
        const int2* Tg = tab + sgBase[gi];
        for (int slot = 0; slot < S; ++slot) {
            const int4* R = (const int4*)(Tg + (slot << 3));   // 64 B, wave-uniform, cache-hot
            const int4 p0 = R[0];
            const int4 p1 = R[1];
            const int4 p2 = R[2];
            const int4 p3 = R[3];
            acc[g * 8 + 0] += __int_as_float(p0.y) * bfld(basep, A2 + p0.x);
            acc[g * 8 + 1] += __int_as_float(p0.w) * bfld(basep, A2 + p0.z);
            acc[g * 8 + 2] += __int_as_float(p1.y) * bfld(basep, A2 + p1.x);
            acc[g * 8 + 3] += __int_as_float(p1.w) * bfld(basep, A2 + p1.z);
            acc[g * 8 + 4] += __int_as_float(p2.y) * bfld(basep, A2 + p2.x);
            acc[g * 8 + 5] += __int_as_float(p2.w) * bfld(basep, A2 + p2.z);
            acc[g * 8 + 6] += __int_as_float(p3.y) * bfld(basep, A2 + p3.x);
            acc[g * 8 + 7] += __int_as_float(p3.w) * bfld(basep, A2 + p3.z);
        }
    }

    // ---- flush: route acc -> true channels through the LDS transpose stage ----
    __syncthreads();                                   // (B1) input region dead
    int tcs[OPW];
#pragma unroll
    for (int k = 0; k < OPW; ++k) {
        const int grp = (k < 8) ? g0 : g1;
        tcs[k] = perm[grp * 8 + (k & 7)];              // true output channel of acc[k]
    }
    const int ob = w * OPW;
    // pass 0: stage true channels [0,128) (all waves write their subset)
#pragma unroll
    for (int k = 0; k < OPW; ++k) {
        const int tc = tcs[k];
        if ((tc >> 7) == 0)
            ldsF[((tc >> 4) & 7) * STG_W + lane * SST + (tc & 15)] = acc[k];
    }
    __syncthreads();                                   // (B2)
    if (w < 8) {
        const int a_  = lane >> 2;     // pixel sub-index 0..15
        const int chq = lane & 3;      // channel quad 0..3
        const float* rb = ldsF + w * STG_W;
#pragma unroll
        for (int s16 = 0; s16 < 4; ++s16) {
            int p = s16 * 16 + a_;
            float2 u0 = *(const float2*)(rb + p * SST + chq * 4);
            float2 u1 = *(const float2*)(rb + p * SST + chq * 4 + 2);
            int poy = iy0 + (p >> 3), pox = ix0 + (p & 7);
            if (poy < OH && pox < OW) {
                float4 o4 = make_float4(u0.x, u0.y, u1.x, u1.y);
                *(float4*)(out + (((size_t)b * OH + poy) * OW + pox) * O_OUT + ob + chq * 4) = o4;
            }
        }
    }
    __syncthreads();                                   // (B3) pass-0 reads done
    // pass 1: stage true channels [128,256)
#pragma unroll
    for (int k = 0; k < OPW; ++k) {
        const int tc = tcs[k];
        if ((tc >> 7) == 1)
            ldsF[((tc >> 4) & 7) * STG_W + lane * SST + (tc & 15)] = acc[k];
    }
    __syncthreads();                                   // (B4)
    if (w >= 8) {
        const int a_  = lane >> 2;
        const int chq = lane & 3;
        const float* rb = ldsF + (w & 7) * STG_W;
#pragma unroll
        for (int s16 = 0; s16 < 4; ++s16) {
            int p = s16 * 16 + a_;
            float2 u0 = *(const float2*)(rb + p * SST + chq * 4);
            float2 u1 = *(const float2*)(rb + p * SST + chq * 4 + 2);
            int poy = iy0 + (p >> 3), pox = ix0 + (p & 7);
            if (poy < OH && pox < OW) {
                float4 o4 = make_float4(u0.x, u0.y, u1.x, u1.y);
                *(float4*)(out + (((size_t)b * OH + poy) * OW + pox) * O_OUT + ob + chq * 4) = o4;
            }
        }
    }
}

// ---------------- host ----------------
extern "C" void kernel_launch(void* const* d_in, const int* in_sizes, int n_in,
                              void* d_out, int out_size, void* d_ws, size_t ws_size,
                              hipStream_t stream) {
    const float* input = (const float*)d_in[0];
    const int*   widx  = (const int*)d_in[1];    // int32 or int64 (runtime-detected)
    const float* wval  = (const float*)d_in[2];
    float* outp = (float*)d_out;
    const int nnz = in_sizes[2];
    const int B = in_sizes[0] / (H_IN * W_IN * C_IN);

    int*  sgS    = (int*)d_ws;                       // 32 ints
    int*  sgBase = sgS + 32;                         // 33 ints
    int*  perm   = (int*)((char*)d_ws + 512);        // 256 ints
    int2* tab    = (int2*)((char*)d_ws + 2048);      // worst case 8*nnz entries

    prep_kernel<<<1, 256, 0, stream>>>(widx, wval, nnz, sgS, sgBase, perm, tab);

    static_assert(LDS_BYTES >= FLUSH_BYTES, "flush pass must fit in input region");
    static_assert(2 * LDS_BYTES <= 160 * 1024, "need 2 blocks/CU");
    hipFuncSetAttribute((const void*)conv_kernel,
                        hipFuncAttributeMaxDynamicSharedMemorySize, LDS_BYTES);
    dim3 grid((OW + TX - 1) / TX, (OH + TY - 1) / TY, B);
    conv_kernel<<<grid, 1024, LDS_BYTES, stream>>>(input, outp, sgS, sgBase, perm, tab);
}